// Round 2
// baseline (512.094 us; speedup 1.0000x reference)
//
#include <hip/hip_runtime.h>

// B=64, S=512, D=256, VOCAB=50000, NC=10, N_STEPS=10 (h=0.1), BN eval.
// RK4 on linear RHS == affine map; 10 steps collapse to z@P10 + c10.
// Round 2: (a) whole prep chain fused into one persistent kernel with grid
// barriers (was 13 dispatches ~200us); (b) k_main reads B-fragments directly
// from global (slab is L2-resident, already in fragment order) -- no B LDS
// staging, no in-loop barriers.

typedef short bf16x8 __attribute__((ext_vector_type(8)));
typedef float f32x4 __attribute__((ext_vector_type(4)));

#define NBLK 256

__device__ __forceinline__ unsigned short f2bf(float f) {
  unsigned u = __float_as_uint(f);
  u += 0x7FFFu + ((u >> 16) & 1u);   // RNE; inputs are normal floats
  return (unsigned short)(u >> 16);
}

// cumulative-phase grid barrier; cnt zeroed by memset before launch.
__device__ __forceinline__ void gsync(unsigned* cnt, unsigned phase) {
  __syncthreads();
  if (threadIdx.x == 0) {
    __threadfence();  // agent-scope release of prior global stores
    __hip_atomic_fetch_add(cnt, 1u, __ATOMIC_ACQ_REL, __HIP_MEMORY_SCOPE_AGENT);
    while (__hip_atomic_load(cnt, __ATOMIC_ACQUIRE, __HIP_MEMORY_SCOPE_AGENT) < phase * NBLK)
      __builtin_amdgcn_s_sleep(2);
  }
  __syncthreads();
}

// ---------------- fused prep: 256 blocks (1/CU), 8 grid barriers ----------------
// mat layout (floats): hA,A2,A3,A4,Mm,P2,P4,P5,P10 @ i*65536; c1,c2,c4,c5,c10 @ 589824+i*256
__global__ __launch_bounds__(256, 1) void k_prep(
    const float* __restrict__ W, const float* __restrict__ bode,
    const float* __restrict__ w3, const float* __restrict__ w4, const float* __restrict__ w5,
    float* mat, unsigned short* slab, unsigned* cnt) {
  float* hA  = mat;
  float* A2  = mat + 65536;
  float* A3  = mat + 131072;
  float* A4  = mat + 196608;
  float* Mm  = mat + 262144;
  float* P2  = mat + 327680;
  float* P4  = mat + 393216;
  float* P5  = mat + 458752;
  float* P10 = mat + 524288;
  float* c1  = mat + 589824;
  float* c2  = c1 + 256;
  float* c4  = c1 + 512;
  float* c5  = c1 + 768;
  float* c10 = c1 + 1024;

  const int blk = blockIdx.x;
  const int j = threadIdx.x;
  __shared__ float sA[256];
  __shared__ float sV[256];

  // ---- S0: hA = 0.1*W^T rows + conv-weight repack (independent of chain) ----
  hA[blk * 256 + j] = 0.1f * W[j * 256 + blk];
  for (int e = blk * 256 + j; e < 12 * 32768; e += 65536) {
    int s = e >> 15, r = e & 32767, kd = r >> 7, o = r & 127;
    const float* w; int kk, jj;
    if (s < 3)      { w = w3; kk = 3; jj = s; }
    else if (s < 7) { w = w4; kk = 4; jj = s - 3; }
    else            { w = w5; kk = 5; jj = s - 7; }
    float val = w[(o * 256 + kd) * kk + jj];
    int kc = kd >> 5, quad = (kd >> 3) & 3, q8 = kd & 7;
    slab[s * 32768 + ((kc * 4 + quad) * 128 + o) * 8 + q8] = f2bf(val);
  }
  gsync(cnt, 1);

  // ---- S1: A2 = hA@hA ----
  sA[j] = hA[blk * 256 + j];
  __syncthreads();
  {
    float a = 0.f;
#pragma unroll 16
    for (int k = 0; k < 256; ++k) a = fmaf(sA[k], hA[k * 256 + j], a);
    A2[blk * 256 + j] = a;
  }
  gsync(cnt, 2);

  // ---- S2: A3 = A2@hA, A4 = A2@A2 (one pass) ----
  sA[j] = A2[blk * 256 + j];
  __syncthreads();
  {
    float a3 = 0.f, a4 = 0.f;
#pragma unroll 8
    for (int k = 0; k < 256; ++k) {
      float av = sA[k];
      a3 = fmaf(av, hA[k * 256 + j], a3);
      a4 = fmaf(av, A2[k * 256 + j], a4);
    }
    A3[blk * 256 + j] = a3;
    A4[blk * 256 + j] = a4;
  }
  gsync(cnt, 3);

  // ---- S3: M = I + hA + A2/2 + A3/6 + A4/24 ; block0: c1 ----
  {
    int e = blk * 256 + j;
    float I = (blk == j) ? 1.f : 0.f;
    Mm[e] = I + hA[e] + A2[e] * 0.5f + A3[e] * (1.f / 6.f) + A4[e] * (1.f / 24.f);
  }
  if (blk == 0) {
    sV[j] = bode[j];
    __syncthreads();
    float a = sV[j];
#pragma unroll 8
    for (int k = 0; k < 256; ++k) {
      int e = k * 256 + j;
      a = fmaf(sV[k], hA[e] * 0.5f + A2[e] * (1.f / 6.f) + A3[e] * (1.f / 24.f), a);
    }
    c1[j] = 0.1f * a;
  }
  gsync(cnt, 4);

  // ---- S4: P2 = M@M ; c2 = c1@M + c1 ----
  sA[j] = Mm[blk * 256 + j];
  if (blk == 0) sV[j] = c1[j];
  __syncthreads();
  {
    float a = 0.f;
#pragma unroll 16
    for (int k = 0; k < 256; ++k) a = fmaf(sA[k], Mm[k * 256 + j], a);
    P2[blk * 256 + j] = a;
  }
  if (blk == 0) {
    float a = sV[j];
#pragma unroll 16
    for (int k = 0; k < 256; ++k) a = fmaf(sV[k], Mm[k * 256 + j], a);
    c2[j] = a;
  }
  gsync(cnt, 5);

  // ---- S5: P4 = P2@P2 ; c4 = c2@P2 + c2 ----
  sA[j] = P2[blk * 256 + j];
  if (blk == 0) sV[j] = c2[j];
  __syncthreads();
  {
    float a = 0.f;
#pragma unroll 16
    for (int k = 0; k < 256; ++k) a = fmaf(sA[k], P2[k * 256 + j], a);
    P4[blk * 256 + j] = a;
  }
  if (blk == 0) {
    float a = sV[j];
#pragma unroll 16
    for (int k = 0; k < 256; ++k) a = fmaf(sV[k], P2[k * 256 + j], a);
    c4[j] = a;
  }
  gsync(cnt, 6);

  // ---- S6: P5 = P4@M ; c5 = c4@M + c1 ----
  sA[j] = P4[blk * 256 + j];
  if (blk == 0) sV[j] = c4[j];
  __syncthreads();
  {
    float a = 0.f;
#pragma unroll 16
    for (int k = 0; k < 256; ++k) a = fmaf(sA[k], Mm[k * 256 + j], a);
    P5[blk * 256 + j] = a;
  }
  if (blk == 0) {
    float a = c1[j];
#pragma unroll 16
    for (int k = 0; k < 256; ++k) a = fmaf(sV[k], Mm[k * 256 + j], a);
    c5[j] = a;
  }
  gsync(cnt, 7);

  // ---- S7: P10 = P5@P5 ; c10 = c5@P5 + c5 ----
  sA[j] = P5[blk * 256 + j];
  if (blk == 0) sV[j] = c5[j];
  __syncthreads();
  {
    float a = 0.f;
#pragma unroll 16
    for (int k = 0; k < 256; ++k) a = fmaf(sA[k], P5[k * 256 + j], a);
    P10[blk * 256 + j] = a;
  }
  if (blk == 0) {
    float a = sV[j];
#pragma unroll 16
    for (int k = 0; k < 256; ++k) a = fmaf(sV[k], P5[k * 256 + j], a);
    c10[j] = a;
  }
  gsync(cnt, 8);

  // ---- S8: node repack (kd = blk, o = j) ----
  {
    float val = P10[blk * 256 + j];
    int kc = blk >> 5, quad = (blk >> 3) & 3, q8 = blk & 7;
    int s = 12 + (j >> 7);
    slab[s * 32768 + ((kc * 4 + quad) * 128 + (j & 127)) * 8 + q8] = f2bf(val);
  }
}

// ---------------- fused main kernel ----------------
// grid 512 = 64 batches x 8 t-chunks of 64. 256 threads = 4 waves.
// LDS: X tile only (68 x 264 bf16, ~36 KB). B-fragments read directly from
// global slab (L2-resident). ONE __syncthreads total; K-loop barrier-free.
__global__ __launch_bounds__(256, 2) void k_main(
    const int* __restrict__ ids, const float* __restrict__ emb,
    const unsigned short* __restrict__ slab, const float* __restrict__ ctot,
    const float* __restrict__ b3, const float* __restrict__ g3, const float* __restrict__ be3,
    const float* __restrict__ b4, const float* __restrict__ g4, const float* __restrict__ be4,
    const float* __restrict__ b5, const float* __restrict__ g5, const float* __restrict__ be5,
    unsigned* __restrict__ featbuf) {
  __shared__ alignas(16) unsigned short Xt[68 * 264];
  __shared__ int ids_s[68];
  const int tid = threadIdx.x;
  const int blk = blockIdx.x;
  const int b = blk >> 3;
  const int t0 = (blk & 7) * 64;
  const int lane = tid & 63;
  const int wave = tid >> 6;
  const int m15 = lane & 15;
  const int quad = lane >> 4;

  if (tid < 68) {
    int t = t0 + tid;
    ids_s[tid] = (t < 512) ? ids[b * 512 + t] : -1;
  }
  __syncthreads();
  for (int i = tid; i < 68 * 64; i += 256) {
    int row = i >> 6, s4 = i & 63;
    uint2 v = make_uint2(0u, 0u);
    int id = ids_s[row];
    if (id >= 0) {
      const float4 f = *(const float4*)(emb + (size_t)id * 256 + s4 * 4);
      v.x = (unsigned)f2bf(f.x) | ((unsigned)f2bf(f.y) << 16);
      v.y = (unsigned)f2bf(f.z) | ((unsigned)f2bf(f.w) << 16);
    }
    *(uint2*)&Xt[row * 264 + s4 * 4] = v;
  }
  __syncthreads();

  const int g_start[5] = {0, 3, 7, 12, 13};
  const int g_cnt[5]   = {3, 4, 5, 1, 1};

  for (int g = 0; g < 5; ++g) {
    f32x4 acc[4][2];
#pragma unroll
    for (int mt = 0; mt < 4; ++mt)
#pragma unroll
      for (int nt = 0; nt < 2; ++nt)
        acc[mt][nt] = (f32x4){0.f, 0.f, 0.f, 0.f};

    for (int ji = 0; ji < g_cnt[g]; ++ji) {
      const int slice = g_start[g] + ji;
      const int shift = (g < 3) ? ji : 0;
      // frag addr: slice*32768 + (kc*4+quad)*1024 + n*8, n = wave*32 + nt*16 + m15
      const unsigned short* bsl = slab + (size_t)slice * 32768 + quad * 1024 + wave * 256 + m15 * 8;
#pragma unroll
      for (int kc = 0; kc < 8; ++kc) {
        const int kd0 = kc * 32 + quad * 8;
        bf16x8 af[4];
#pragma unroll
        for (int mt = 0; mt < 4; ++mt)
          af[mt] = *(const bf16x8*)&Xt[(shift + mt * 16 + m15) * 264 + kd0];
        const bf16x8 bf0 = *(const bf16x8*)&bsl[kc * 4096];
        const bf16x8 bf1 = *(const bf16x8*)&bsl[kc * 4096 + 128];
#pragma unroll
        for (int mt = 0; mt < 4; ++mt)
          acc[mt][0] = __builtin_amdgcn_mfma_f32_16x16x32_bf16(af[mt], bf0, acc[mt][0], 0, 0, 0);
#pragma unroll
        for (int mt = 0; mt < 4; ++mt)
          acc[mt][1] = __builtin_amdgcn_mfma_f32_16x16x32_bf16(af[mt], bf1, acc[mt][1], 0, 0, 0);
      }
    }

    // epilogue: C/D layout col=lane&15, row=(lane>>4)*4+reg
    if (g < 3) {
      const int k = g + 3;
      const float* bb  = (g == 0) ? b3 : (g == 1) ? b4 : b5;
      const float* gg  = (g == 0) ? g3 : (g == 1) ? g4 : g5;
      const float* bbe = (g == 0) ? be3 : (g == 1) ? be4 : be5;
      const int off = 256 + g * 128;
      const int tmax = 512 - k;
#pragma unroll
      for (int nt = 0; nt < 2; ++nt) {
        const int n = (wave * 2 + nt) * 16 + m15;
        const float sc = gg[n] * 0.9999950000375f;  // g * 1/sqrt(1+1e-5)
        const float sh = fmaf(sc, bb[n], bbe[n]);
        float mx = 0.f;  // relu floor doubles as init
#pragma unroll
        for (int mt = 0; mt < 4; ++mt)
#pragma unroll
          for (int r = 0; r < 4; ++r) {
            const int t = t0 + mt * 16 + quad * 4 + r;
            const float v = fmaf(sc, acc[mt][nt][r], sh);
            if (t <= tmax) mx = fmaxf(mx, v);
          }
        mx = fmaxf(mx, __shfl_xor(mx, 16));
        mx = fmaxf(mx, __shfl_xor(mx, 32));
        if (quad == 0) atomicMax(&featbuf[b * 640 + off + n], __float_as_uint(mx));
      }
    } else {
      const int base = (g == 3) ? 0 : 128;
#pragma unroll
      for (int nt = 0; nt < 2; ++nt) {
        const int n = (wave * 2 + nt) * 16 + m15;
        const float ct = ctot[base + n];
        float mx = -3.4e38f;
#pragma unroll
        for (int mt = 0; mt < 4; ++mt)
#pragma unroll
          for (int r = 0; r < 4; ++r)
            mx = fmaxf(mx, acc[mt][nt][r] + ct);
        mx = fmaxf(mx, __shfl_xor(mx, 16));
        mx = fmaxf(mx, __shfl_xor(mx, 32));
        if (quad == 0) {
          unsigned bits = __float_as_uint(mx);
          unsigned key = (bits & 0x80000000u) ? ~bits : (bits | 0x80000000u);
          atomicMax(&featbuf[b * 640 + base + n], key);
        }
      }
    }
  }
}

// ---------------- classifier ----------------
__global__ void k_fin(const unsigned* __restrict__ featbuf, const float* __restrict__ wc,
                      const float* __restrict__ bc, float* __restrict__ out) {
  int b = blockIdx.x, lane = threadIdx.x;  // 64 threads = 1 wave
  float p[10];
#pragma unroll
  for (int c = 0; c < 10; ++c) p[c] = 0.f;
  for (int f = lane; f < 640; f += 64) {
    unsigned u = featbuf[b * 640 + f];
    float v;
    if (f < 256) v = (u & 0x80000000u) ? __uint_as_float(u ^ 0x80000000u) : __uint_as_float(~u);
    else v = __uint_as_float(u);
#pragma unroll
    for (int c = 0; c < 10; ++c) p[c] = fmaf(v, wc[c * 640 + f], p[c]);
  }
#pragma unroll
  for (int c = 0; c < 10; ++c) {
    float s = p[c];
#pragma unroll
    for (int off = 32; off > 0; off >>= 1) s += __shfl_down(s, off);
    if (lane == 0) out[b * 10 + c] = s + bc[c];
  }
}

// ---------------- launcher ----------------
extern "C" void kernel_launch(void* const* d_in, const int* in_sizes, int n_in,
                              void* d_out, int out_size, void* d_ws, size_t ws_size,
                              hipStream_t stream) {
  (void)in_sizes; (void)n_in; (void)out_size; (void)ws_size;
  const int*   ids  = (const int*)d_in[0];
  const float* emb  = (const float*)d_in[1];
  const float* W    = (const float*)d_in[2];
  const float* bode = (const float*)d_in[3];
  const float* w3   = (const float*)d_in[4];
  const float* b3   = (const float*)d_in[5];
  const float* g3   = (const float*)d_in[6];
  const float* be3  = (const float*)d_in[7];
  const float* w4   = (const float*)d_in[8];
  const float* b4   = (const float*)d_in[9];
  const float* g4   = (const float*)d_in[10];
  const float* be4  = (const float*)d_in[11];
  const float* w5   = (const float*)d_in[12];
  const float* b5   = (const float*)d_in[13];
  const float* g5   = (const float*)d_in[14];
  const float* be5  = (const float*)d_in[15];
  const float* wc   = (const float*)d_in[16];
  const float* bc   = (const float*)d_in[17];
  float* out = (float*)d_out;

  float* wsf = (float*)d_ws;
  unsigned* cnt = (unsigned*)wsf;                       // 64 floats reserved
  unsigned* featbuf = (unsigned*)(wsf + 64);            // 64*640 uints
  float* mat = wsf + 65536;                             // matrices + vectors
  unsigned short* slab = (unsigned short*)(mat + 591104); // 14 slices * 32768 bf16
  const float* c10 = mat + 589824 + 1024;

  // zero barrier counter + featbuf in one memset (contiguous)
  hipMemsetAsync(cnt, 0, (64 + 64 * 640) * sizeof(unsigned), stream);

  hipLaunchKernelGGL(k_prep, dim3(NBLK), dim3(256), 0, stream,
                     W, bode, w3, w4, w5, mat, slab, cnt);
  hipLaunchKernelGGL(k_main, dim3(512), dim3(256), 0, stream,
                     ids, emb, slab, c10,
                     b3, g3, be3, b4, g4, be4, b5, g5, be5, featbuf);
  hipLaunchKernelGGL(k_fin, dim3(64), dim3(64), 0, stream, featbuf, wc, bc, out);
}

// Round 4
// 304.722 us; speedup vs baseline: 1.6805x; 1.6805x over previous
//
#include <hip/hip_runtime.h>

// B=64, S=512, D=256, VOCAB=50000, NC=10, N_STEPS=10 (h=0.1), BN eval.
// RK4 on linear RHS == affine map; 10 steps collapse to z@P10 + c10.
// Round 4: same as round 3 (RELAXED flag polling barrier) but the exit
// acquire is a single __hip_atomic_load ACQUIRE (this ROCm has no
// __hip_atomic_fence builtin).

typedef short bf16x8 __attribute__((ext_vector_type(8)));
typedef float f32x4 __attribute__((ext_vector_type(4)));

#define NBLK 256

__device__ __forceinline__ unsigned short f2bf(float f) {
  unsigned u = __float_as_uint(f);
  u += 0x7FFFu + ((u >> 16) & 1u);   // RNE; inputs are normal floats
  return (unsigned short)(u >> 16);
}

// two-location grid barrier; cnt/flag zeroed by memset before launch.
// cnt: cumulative arrivals. flag: highest completed phase.
__device__ __forceinline__ void gsync(unsigned* cnt, unsigned* flag, unsigned phase) {
  __syncthreads();
  if (threadIdx.x == 0) {
    unsigned old = __hip_atomic_fetch_add(cnt, 1u, __ATOMIC_ACQ_REL, __HIP_MEMORY_SCOPE_AGENT);
    if (old == phase * NBLK - 1)
      __hip_atomic_store(flag, phase, __ATOMIC_RELEASE, __HIP_MEMORY_SCOPE_AGENT);
    // RELAXED poll: plain LLC load, no invalidate per iteration.
    while (__hip_atomic_load(flag, __ATOMIC_RELAXED, __HIP_MEMORY_SCOPE_AGENT) < phase)
      __builtin_amdgcn_s_sleep(4);
    // single acquire op = one cache invalidate, makes prior stores visible
    (void)__hip_atomic_load(flag, __ATOMIC_ACQUIRE, __HIP_MEMORY_SCOPE_AGENT);
  }
  __syncthreads();
}

// ---------------- fused prep: 256 blocks (1/CU), 8 grid barriers ----------------
// mat layout (floats): hA,A2,A3,A4,Mm,P2,P4,P5,P10 @ i*65536; c1,c2,c4,c5,c10 @ 589824+i*256
__global__ __launch_bounds__(256, 1) void k_prep(
    const float* __restrict__ W, const float* __restrict__ bode,
    const float* __restrict__ w3, const float* __restrict__ w4, const float* __restrict__ w5,
    float* mat, unsigned short* slab, unsigned* cnt, unsigned* flag) {
  float* hA  = mat;
  float* A2  = mat + 65536;
  float* A3  = mat + 131072;
  float* A4  = mat + 196608;
  float* Mm  = mat + 262144;
  float* P2  = mat + 327680;
  float* P4  = mat + 393216;
  float* P5  = mat + 458752;
  float* P10 = mat + 524288;
  float* c1  = mat + 589824;
  float* c2  = c1 + 256;
  float* c4  = c1 + 512;
  float* c5  = c1 + 768;
  float* c10 = c1 + 1024;

  const int blk = blockIdx.x;
  const int j = threadIdx.x;
  __shared__ float sA[256];
  __shared__ float sV[256];

  // ---- S0: hA = 0.1*W^T rows + conv-weight repack (independent of chain) ----
  hA[blk * 256 + j] = 0.1f * W[j * 256 + blk];
  for (int e = blk * 256 + j; e < 12 * 32768; e += 65536) {
    int s = e >> 15, r = e & 32767, kd = r >> 7, o = r & 127;
    const float* w; int kk, jj;
    if (s < 3)      { w = w3; kk = 3; jj = s; }
    else if (s < 7) { w = w4; kk = 4; jj = s - 3; }
    else            { w = w5; kk = 5; jj = s - 7; }
    float val = w[(o * 256 + kd) * kk + jj];
    int kc = kd >> 5, quad = (kd >> 3) & 3, q8 = kd & 7;
    slab[s * 32768 + ((kc * 4 + quad) * 128 + o) * 8 + q8] = f2bf(val);
  }
  gsync(cnt, flag, 1);

  // ---- S1: A2 = hA@hA ----
  sA[j] = hA[blk * 256 + j];
  __syncthreads();
  {
    float a = 0.f;
#pragma unroll 16
    for (int k = 0; k < 256; ++k) a = fmaf(sA[k], hA[k * 256 + j], a);
    A2[blk * 256 + j] = a;
  }
  gsync(cnt, flag, 2);

  // ---- S2: A3 = A2@hA, A4 = A2@A2 (one pass) ----
  sA[j] = A2[blk * 256 + j];
  __syncthreads();
  {
    float a3 = 0.f, a4 = 0.f;
#pragma unroll 8
    for (int k = 0; k < 256; ++k) {
      float av = sA[k];
      a3 = fmaf(av, hA[k * 256 + j], a3);
      a4 = fmaf(av, A2[k * 256 + j], a4);
    }
    A3[blk * 256 + j] = a3;
    A4[blk * 256 + j] = a4;
  }
  gsync(cnt, flag, 3);

  // ---- S3: M = I + hA + A2/2 + A3/6 + A4/24 ; block0: c1 ----
  {
    int e = blk * 256 + j;
    float I = (blk == j) ? 1.f : 0.f;
    Mm[e] = I + hA[e] + A2[e] * 0.5f + A3[e] * (1.f / 6.f) + A4[e] * (1.f / 24.f);
  }
  if (blk == 0) {
    sV[j] = bode[j];
    __syncthreads();
    float a = sV[j];
#pragma unroll 8
    for (int k = 0; k < 256; ++k) {
      int e = k * 256 + j;
      a = fmaf(sV[k], hA[e] * 0.5f + A2[e] * (1.f / 6.f) + A3[e] * (1.f / 24.f), a);
    }
    c1[j] = 0.1f * a;
  }
  gsync(cnt, flag, 4);

  // ---- S4: P2 = M@M ; c2 = c1@M + c1 ----
  sA[j] = Mm[blk * 256 + j];
  if (blk == 0) sV[j] = c1[j];
  __syncthreads();
  {
    float a = 0.f;
#pragma unroll 16
    for (int k = 0; k < 256; ++k) a = fmaf(sA[k], Mm[k * 256 + j], a);
    P2[blk * 256 + j] = a;
  }
  if (blk == 0) {
    float a = sV[j];
#pragma unroll 16
    for (int k = 0; k < 256; ++k) a = fmaf(sV[k], Mm[k * 256 + j], a);
    c2[j] = a;
  }
  gsync(cnt, flag, 5);

  // ---- S5: P4 = P2@P2 ; c4 = c2@P2 + c2 ----
  sA[j] = P2[blk * 256 + j];
  if (blk == 0) sV[j] = c2[j];
  __syncthreads();
  {
    float a = 0.f;
#pragma unroll 16
    for (int k = 0; k < 256; ++k) a = fmaf(sA[k], P2[k * 256 + j], a);
    P4[blk * 256 + j] = a;
  }
  if (blk == 0) {
    float a = sV[j];
#pragma unroll 16
    for (int k = 0; k < 256; ++k) a = fmaf(sV[k], P2[k * 256 + j], a);
    c4[j] = a;
  }
  gsync(cnt, flag, 6);

  // ---- S6: P5 = P4@M ; c5 = c4@M + c1 ----
  sA[j] = P4[blk * 256 + j];
  if (blk == 0) sV[j] = c4[j];
  __syncthreads();
  {
    float a = 0.f;
#pragma unroll 16
    for (int k = 0; k < 256; ++k) a = fmaf(sA[k], Mm[k * 256 + j], a);
    P5[blk * 256 + j] = a;
  }
  if (blk == 0) {
    float a = c1[j];
#pragma unroll 16
    for (int k = 0; k < 256; ++k) a = fmaf(sV[k], Mm[k * 256 + j], a);
    c5[j] = a;
  }
  gsync(cnt, flag, 7);

  // ---- S7: P10 = P5@P5 ; c10 = c5@P5 + c5 ----
  sA[j] = P5[blk * 256 + j];
  if (blk == 0) sV[j] = c5[j];
  __syncthreads();
  {
    float a = 0.f;
#pragma unroll 16
    for (int k = 0; k < 256; ++k) a = fmaf(sA[k], P5[k * 256 + j], a);
    P10[blk * 256 + j] = a;
  }
  if (blk == 0) {
    float a = sV[j];
#pragma unroll 16
    for (int k = 0; k < 256; ++k) a = fmaf(sV[k], P5[k * 256 + j], a);
    c10[j] = a;
  }
  gsync(cnt, flag, 8);

  // ---- S8: node repack (kd = blk, o = j) ----
  {
    float val = P10[blk * 256 + j];
    int kc = blk >> 5, quad = (blk >> 3) & 3, q8 = blk & 7;
    int s = 12 + (j >> 7);
    slab[s * 32768 + ((kc * 4 + quad) * 128 + (j & 127)) * 8 + q8] = f2bf(val);
  }
}

// ---------------- fused main kernel ----------------
// grid 512 = 64 batches x 8 t-chunks of 64. 256 threads = 4 waves.
// LDS: X tile only (68 x 264 bf16, ~36 KB). B-fragments read directly from
// global slab (L2-resident). ONE __syncthreads total; K-loop barrier-free.
__global__ __launch_bounds__(256, 2) void k_main(
    const int* __restrict__ ids, const float* __restrict__ emb,
    const unsigned short* __restrict__ slab, const float* __restrict__ ctot,
    const float* __restrict__ b3, const float* __restrict__ g3, const float* __restrict__ be3,
    const float* __restrict__ b4, const float* __restrict__ g4, const float* __restrict__ be4,
    const float* __restrict__ b5, const float* __restrict__ g5, const float* __restrict__ be5,
    unsigned* __restrict__ featbuf) {
  __shared__ alignas(16) unsigned short Xt[68 * 264];
  __shared__ int ids_s[68];
  const int tid = threadIdx.x;
  const int blk = blockIdx.x;
  const int b = blk >> 3;
  const int t0 = (blk & 7) * 64;
  const int lane = tid & 63;
  const int wave = tid >> 6;
  const int m15 = lane & 15;
  const int quad = lane >> 4;

  if (tid < 68) {
    int t = t0 + tid;
    ids_s[tid] = (t < 512) ? ids[b * 512 + t] : -1;
  }
  __syncthreads();
  for (int i = tid; i < 68 * 64; i += 256) {
    int row = i >> 6, s4 = i & 63;
    uint2 v = make_uint2(0u, 0u);
    int id = ids_s[row];
    if (id >= 0) {
      const float4 f = *(const float4*)(emb + (size_t)id * 256 + s4 * 4);
      v.x = (unsigned)f2bf(f.x) | ((unsigned)f2bf(f.y) << 16);
      v.y = (unsigned)f2bf(f.z) | ((unsigned)f2bf(f.w) << 16);
    }
    *(uint2*)&Xt[row * 264 + s4 * 4] = v;
  }
  __syncthreads();

  const int g_start[5] = {0, 3, 7, 12, 13};
  const int g_cnt[5]   = {3, 4, 5, 1, 1};

  for (int g = 0; g < 5; ++g) {
    f32x4 acc[4][2];
#pragma unroll
    for (int mt = 0; mt < 4; ++mt)
#pragma unroll
      for (int nt = 0; nt < 2; ++nt)
        acc[mt][nt] = (f32x4){0.f, 0.f, 0.f, 0.f};

    for (int ji = 0; ji < g_cnt[g]; ++ji) {
      const int slice = g_start[g] + ji;
      const int shift = (g < 3) ? ji : 0;
      // frag addr: slice*32768 + (kc*4+quad)*1024 + n*8, n = wave*32 + nt*16 + m15
      const unsigned short* bsl = slab + (size_t)slice * 32768 + quad * 1024 + wave * 256 + m15 * 8;
#pragma unroll
      for (int kc = 0; kc < 8; ++kc) {
        const int kd0 = kc * 32 + quad * 8;
        bf16x8 af[4];
#pragma unroll
        for (int mt = 0; mt < 4; ++mt)
          af[mt] = *(const bf16x8*)&Xt[(shift + mt * 16 + m15) * 264 + kd0];
        const bf16x8 bf0 = *(const bf16x8*)&bsl[kc * 4096];
        const bf16x8 bf1 = *(const bf16x8*)&bsl[kc * 4096 + 128];
#pragma unroll
        for (int mt = 0; mt < 4; ++mt)
          acc[mt][0] = __builtin_amdgcn_mfma_f32_16x16x32_bf16(af[mt], bf0, acc[mt][0], 0, 0, 0);
#pragma unroll
        for (int mt = 0; mt < 4; ++mt)
          acc[mt][1] = __builtin_amdgcn_mfma_f32_16x16x32_bf16(af[mt], bf1, acc[mt][1], 0, 0, 0);
      }
    }

    // epilogue: C/D layout col=lane&15, row=(lane>>4)*4+reg
    if (g < 3) {
      const int k = g + 3;
      const float* bb  = (g == 0) ? b3 : (g == 1) ? b4 : b5;
      const float* gg  = (g == 0) ? g3 : (g == 1) ? g4 : g5;
      const float* bbe = (g == 0) ? be3 : (g == 1) ? be4 : be5;
      const int off = 256 + g * 128;
      const int tmax = 512 - k;
#pragma unroll
      for (int nt = 0; nt < 2; ++nt) {
        const int n = (wave * 2 + nt) * 16 + m15;
        const float sc = gg[n] * 0.9999950000375f;  // g * 1/sqrt(1+1e-5)
        const float sh = fmaf(sc, bb[n], bbe[n]);
        float mx = 0.f;  // relu floor doubles as init
#pragma unroll
        for (int mt = 0; mt < 4; ++mt)
#pragma unroll
          for (int r = 0; r < 4; ++r) {
            const int t = t0 + mt * 16 + quad * 4 + r;
            const float v = fmaf(sc, acc[mt][nt][r], sh);
            if (t <= tmax) mx = fmaxf(mx, v);
          }
        mx = fmaxf(mx, __shfl_xor(mx, 16));
        mx = fmaxf(mx, __shfl_xor(mx, 32));
        if (quad == 0) atomicMax(&featbuf[b * 640 + off + n], __float_as_uint(mx));
      }
    } else {
      const int base = (g == 3) ? 0 : 128;
#pragma unroll
      for (int nt = 0; nt < 2; ++nt) {
        const int n = (wave * 2 + nt) * 16 + m15;
        const float ct = ctot[base + n];
        float mx = -3.4e38f;
#pragma unroll
        for (int mt = 0; mt < 4; ++mt)
#pragma unroll
          for (int r = 0; r < 4; ++r)
            mx = fmaxf(mx, acc[mt][nt][r] + ct);
        mx = fmaxf(mx, __shfl_xor(mx, 16));
        mx = fmaxf(mx, __shfl_xor(mx, 32));
        if (quad == 0) {
          unsigned bits = __float_as_uint(mx);
          unsigned key = (bits & 0x80000000u) ? ~bits : (bits | 0x80000000u);
          atomicMax(&featbuf[b * 640 + base + n], key);
        }
      }
    }
  }
}

// ---------------- classifier ----------------
__global__ void k_fin(const unsigned* __restrict__ featbuf, const float* __restrict__ wc,
                      const float* __restrict__ bc, float* __restrict__ out) {
  int b = blockIdx.x, lane = threadIdx.x;  // 64 threads = 1 wave
  float p[10];
#pragma unroll
  for (int c = 0; c < 10; ++c) p[c] = 0.f;
  for (int f = lane; f < 640; f += 64) {
    unsigned u = featbuf[b * 640 + f];
    float v;
    if (f < 256) v = (u & 0x80000000u) ? __uint_as_float(u ^ 0x80000000u) : __uint_as_float(~u);
    else v = __uint_as_float(u);
#pragma unroll
    for (int c = 0; c < 10; ++c) p[c] = fmaf(v, wc[c * 640 + f], p[c]);
  }
#pragma unroll
  for (int c = 0; c < 10; ++c) {
    float s = p[c];
#pragma unroll
    for (int off = 32; off > 0; off >>= 1) s += __shfl_down(s, off);
    if (lane == 0) out[b * 10 + c] = s + bc[c];
  }
}

// ---------------- launcher ----------------
extern "C" void kernel_launch(void* const* d_in, const int* in_sizes, int n_in,
                              void* d_out, int out_size, void* d_ws, size_t ws_size,
                              hipStream_t stream) {
  (void)in_sizes; (void)n_in; (void)out_size; (void)ws_size;
  const int*   ids  = (const int*)d_in[0];
  const float* emb  = (const float*)d_in[1];
  const float* W    = (const float*)d_in[2];
  const float* bode = (const float*)d_in[3];
  const float* w3   = (const float*)d_in[4];
  const float* b3   = (const float*)d_in[5];
  const float* g3   = (const float*)d_in[6];
  const float* be3  = (const float*)d_in[7];
  const float* w4   = (const float*)d_in[8];
  const float* b4   = (const float*)d_in[9];
  const float* g4   = (const float*)d_in[10];
  const float* be4  = (const float*)d_in[11];
  const float* w5   = (const float*)d_in[12];
  const float* b5   = (const float*)d_in[13];
  const float* g5   = (const float*)d_in[14];
  const float* be5  = (const float*)d_in[15];
  const float* wc   = (const float*)d_in[16];
  const float* bc   = (const float*)d_in[17];
  float* out = (float*)d_out;

  float* wsf = (float*)d_ws;
  unsigned* cnt  = (unsigned*)wsf;                      // slot 0
  unsigned* flag = (unsigned*)wsf + 32;                 // separate cache line
  unsigned* featbuf = (unsigned*)(wsf + 64);            // 64*640 uints
  float* mat = wsf + 65536;                             // matrices + vectors
  unsigned short* slab = (unsigned short*)(mat + 591104); // 14 slices * 32768 bf16
  const float* c10 = mat + 589824 + 1024;

  // zero cnt + flag + featbuf in one memset (contiguous)
  (void)hipMemsetAsync(cnt, 0, (64 + 64 * 640) * sizeof(unsigned), stream);

  hipLaunchKernelGGL(k_prep, dim3(NBLK), dim3(256), 0, stream,
                     W, bode, w3, w4, w5, mat, slab, cnt, flag);
  hipLaunchKernelGGL(k_main, dim3(512), dim3(256), 0, stream,
                     ids, emb, slab, c10,
                     b3, g3, be3, b4, g4, be4, b5, g5, be5, featbuf);
  hipLaunchKernelGGL(k_fin, dim3(64), dim3(64), 0, stream, featbuf, wc, bc, out);
}